// Round 1
// baseline (120.978 us; speedup 1.0000x reference)
//
#include <hip/hip_runtime.h>

// CrossNet: xi = x0; for l in 0..2: s = dot(xi, W[l]); xi = x0*s + B[l] + xi
// BATCH=16384, DIM=1024, ORDER=3, fp32.
// One 64-lane wave per row; 16 floats/lane of x0 and xi live in registers.
// Memory-bound: 64 MiB read (x0) + 64 MiB write (out); W/B are 12 KiB (L2-hit).

#define CN_BATCH 16384
#define CN_DIM   1024
#define CN_ORDER 3

__global__ __launch_bounds__(256) void
crossnet_kernel(const float* __restrict__ x0,
                const float* __restrict__ W,
                const float* __restrict__ B,
                float* __restrict__ out)
{
    const int tid  = threadIdx.x;
    const int wave = tid >> 6;          // 0..3 waves per block
    const int lane = tid & 63;
    const int row  = blockIdx.x * 4 + wave;

    const float* __restrict__ xr = x0 + (size_t)row * CN_DIM;

    // lane handles elements chunk*256 + lane*4 .. +3, chunk = 0..3 (coalesced 16B/lane)
    float4 x[4], xi[4];
#pragma unroll
    for (int c = 0; c < 4; ++c) {
        x[c]  = *reinterpret_cast<const float4*>(xr + c * 256 + lane * 4);
        xi[c] = x[c];
    }

#pragma unroll
    for (int l = 0; l < CN_ORDER; ++l) {
        const float* __restrict__ wl = W + l * CN_DIM;
        const float* __restrict__ bl = B + l * CN_DIM;

        float4 w[4];
#pragma unroll
        for (int c = 0; c < 4; ++c)
            w[c] = *reinterpret_cast<const float4*>(wl + c * 256 + lane * 4);

        // per-lane partial dot product (16 elements)
        float s = 0.f;
#pragma unroll
        for (int c = 0; c < 4; ++c) {
            s += xi[c].x * w[c].x;
            s += xi[c].y * w[c].y;
            s += xi[c].z * w[c].z;
            s += xi[c].w * w[c].w;
        }

        // 64-lane butterfly reduction — every lane ends with the full sum
#pragma unroll
        for (int off = 1; off < 64; off <<= 1)
            s += __shfl_xor(s, off, 64);

        // xi += x0 * s + B[l]
#pragma unroll
        for (int c = 0; c < 4; ++c) {
            const float4 b = *reinterpret_cast<const float4*>(bl + c * 256 + lane * 4);
            xi[c].x = fmaf(x[c].x, s, xi[c].x + b.x);
            xi[c].y = fmaf(x[c].y, s, xi[c].y + b.y);
            xi[c].z = fmaf(x[c].z, s, xi[c].z + b.z);
            xi[c].w = fmaf(x[c].w, s, xi[c].w + b.w);
        }
    }

    float* __restrict__ orow = out + (size_t)row * CN_DIM;
#pragma unroll
    for (int c = 0; c < 4; ++c)
        *reinterpret_cast<float4*>(orow + c * 256 + lane * 4) = xi[c];
}

extern "C" void kernel_launch(void* const* d_in, const int* in_sizes, int n_in,
                              void* d_out, int out_size, void* d_ws, size_t ws_size,
                              hipStream_t stream)
{
    const float* x0 = (const float*)d_in[0];   // [16384, 1024]
    const float* W  = (const float*)d_in[1];   // [3, 1024]
    const float* B  = (const float*)d_in[2];   // [3, 1024]
    float* out      = (float*)d_out;           // [16384, 1024]

    const int rows_per_block = 4;              // 4 waves of 64
    dim3 grid(CN_BATCH / rows_per_block);
    dim3 block(256);
    crossnet_kernel<<<grid, block, 0, stream>>>(x0, W, B, out);
}